// Round 1
// 523.268 us; speedup vs baseline: 1.1259x; 1.1259x over previous
//
#include <hip/hip_runtime.h>
#include <math.h>

// Problem constants (fixed by setup_inputs): B=8, N=131072, C=76
#define N_PER   131072
#define NBATCH  8
#define REGC    76
#define TOTAL   (NBATCH * N_PER)      // 1,048,576
#define TILE    2048                  // elements per radix block
#define NBLKSEG (N_PER / TILE)        // 64
#define BINS    256
#define SCTH    512                   // scatter threads
#define CHUNKS  (TILE / SCTH)         // 4

// ---------------------------------------------------------------------------
// key transform: float -> uint such that ascending uint sort == descending
// float sort; stable LSD radix preserves original index order on ties.
__device__ __forceinline__ unsigned desc_key(float f) {
    unsigned u = __float_as_uint(f);
    return (u & 0x80000000u) ? u : ~(u | 0x80000000u);
}

// ---------------------------------------------------------------------------
// Stage 1: decode boxes (linear order). Keys are derived from scores on the
// fly by the sort passes; no key/payload materialization here.
__global__ __launch_bounds__(256) void decode_kernel(
    const float* __restrict__ scores, const float* __restrict__ reg,
    const float* __restrict__ xyz, const float* __restrict__ anchor,
    float* __restrict__ boxes8)
{
    int p = blockIdx.x * 256 + threadIdx.x;           // 0 .. TOTAL-1
    const float* r = reg + (size_t)p * REGC;          // row is 304B, 16B aligned
    const float4* r4 = (const float4*)r;

    float4 q0 = r4[0],  q1 = r4[1],  q2 = r4[2];      // x bins [0:12]
    float4 q3 = r4[3],  q4 = r4[4],  q5 = r4[5];      // z bins [12:24]
    float4 s0 = r4[12], s1 = r4[13], s2 = r4[14], s3 = r4[15]; // [48:64]
    float4 tt = r4[18];                                // [72:76]

    float xa[12] = {q0.x,q0.y,q0.z,q0.w, q1.x,q1.y,q1.z,q1.w, q2.x,q2.y,q2.z,q2.w};
    float za[12] = {q3.x,q3.y,q3.z,q3.w, q4.x,q4.y,q4.z,q4.w, q5.x,q5.y,q5.z,q5.w};
    float ra[12] = {s0.y,s0.z,s0.w, s1.x,s1.y,s1.z,s1.w, s2.x,s2.y,s2.z,s2.w, s3.x};

    int xb = 0; float xm = xa[0];
#pragma unroll
    for (int c = 1; c < 12; ++c) { if (xa[c] > xm) { xm = xa[c]; xb = c; } }
    int zb = 0; float zm = za[0];
#pragma unroll
    for (int c = 1; c < 12; ++c) { if (za[c] > zm) { zm = za[c]; zb = c; } }
    int yb = 0; float ym = ra[0];
#pragma unroll
    for (int c = 1; c < 12; ++c) { if (ra[c] > ym) { ym = ra[c]; yb = c; } }

    float x_res  = r[24 + xb];
    float z_res  = r[36 + zb];
    float ry_res = r[61 + yb];

    float rx = xyz[(size_t)p * 3 + 0];
    float ryy = xyz[(size_t)p * 3 + 1];
    float rz = xyz[(size_t)p * 3 + 2];
    float a0 = anchor[0], a1 = anchor[1], a2 = anchor[2];

    const float APC    = (float)(2.0 * M_PI / 12.0);
    const float HAPC   = (float)(M_PI / 12.0);
    const float TWO_PI = (float)(2.0 * M_PI);
    const float PI_F   = (float)M_PI;

    float vry = __fadd_rn(__fmul_rn((float)yb, APC), __fmul_rn(ry_res, HAPC));
    float m = fmodf(vry, TWO_PI);
    if (m < 0.0f) m += TWO_PI;
    if (m > PI_F) m -= TWO_PI;

    float h = tt.y * a0 + a0;
    float w = tt.z * a1 + a1;
    float l = tt.w * a2 + a2;

    float ox = (((float)xb * 0.5f + 0.25f - 3.0f) + x_res * 0.5f) + rx;
    float oz = (((float)zb * 0.5f + 0.25f - 3.0f) + z_res * 0.5f) + rz;
    float oy = (ryy + s0.x) + h * 0.5f;   // post_process: y + h/2

    float sc = scores[p];

    float4* ob = (float4*)(boxes8 + (size_t)p * 8);
    ob[0] = make_float4(ox, oy, oz, h);
    ob[1] = make_float4(w, l, m, sc);
}

// ---------------------------------------------------------------------------
// Stage 2a: per-block digit histogram -> ushort hist[seg][blk][bin].
// XCD-pinned: seg = blockIdx.x & 7 keeps each segment's keys on one L2.
template<int PASS>
__global__ __launch_bounds__(256) void hist_kernel(
    const float* __restrict__ scores, const unsigned* __restrict__ keyIn,
    unsigned short* __restrict__ hist)
{
    __shared__ unsigned h[BINS];
    int tid = threadIdx.x;
    h[tid] = 0;
    __syncthreads();
    int id = blockIdx.x;
    int seg = id & 7, blk = id >> 3;
    size_t base = (size_t)seg * N_PER + (size_t)blk * TILE;
#pragma unroll
    for (int c = 0; c < TILE / 256; ++c) {
        unsigned key;
        if (PASS == 0) key = desc_key(scores[base + c * 256 + tid]);
        else           key = keyIn[base + c * 256 + tid];
        atomicAdd(&h[(key >> (PASS * 8)) & 255u], 1u);
    }
    __syncthreads();
    hist[(size_t)(seg * NBLKSEG + blk) * BINS + tid] = (unsigned short)h[tid];
}

// ---------------------------------------------------------------------------
// Stage 2b: scatter. Self-service offsets (no scan kernel): each block reads
// the full ushort hist for its segment (L2-hot, 64x512B) and computes
// base[bin] + prefix-over-earlier-blocks itself. All CHUNKS ranked in
// parallel with elements in registers (ballot match), one column-prefix pass,
// then LDS-staged placement so global stores are coalesced.
template<int PASS>
__global__ __launch_bounds__(512) void scatter_kernel(
    const float* __restrict__ scores,
    const unsigned* __restrict__ keyIn, const unsigned* __restrict__ payIn,
    unsigned* __restrict__ keyOut, unsigned* __restrict__ payOut,
    const unsigned short* __restrict__ hist)
{
    __shared__ unsigned whist[CHUNKS * 8][BINS];   // 32 KB
    __shared__ unsigned skey[TILE];                // 8 KB
    __shared__ unsigned spay[TILE];                // 8 KB
    __shared__ unsigned offs[BINS];                // global pos of block's 1st elem of bin
    __shared__ unsigned lexcl[BINS];               // local digit base in [0,TILE)
    __shared__ unsigned wsum[4];

    const int tid  = threadIdx.x;
    const int wave = tid >> 6, lane = tid & 63;
    const unsigned long long lmask = (1ull << lane) - 1ull;
    const int id  = blockIdx.x;
    const int seg = id & 7, blk = id >> 3;         // XCD-pinned by segment
    const size_t segbase = (size_t)seg * N_PER;
    const int gbase = blk * TILE;

    // --- startup: read per-segment hist (L2), zero whist -------------------
    unsigned my_pref = 0, my_tot = 0;
    if (tid < BINS) {
        const unsigned short* hp = hist + (size_t)(seg * NBLKSEG) * BINS + tid;
        unsigned pref = 0, tot = 0;
#pragma unroll
        for (int b = 0; b < NBLKSEG; ++b) {
            unsigned c = hp[(size_t)b * BINS];
            tot += c;
            if (b < blk) pref += c;
        }
        my_pref = pref; my_tot = tot;
    } else {
        int z = tid - BINS;                        // 0..255
        unsigned* wf = &whist[0][0];
#pragma unroll
        for (int k = 0; k < CHUNKS * 8; ++k) wf[k * BINS + z] = 0;  // conflict-free
    }
    __syncthreads();

    // exclusive scan of bin totals -> segment base (shfl within wave + combine)
    unsigned my_base = 0;
    if (tid < BINS) {
        unsigned v = my_tot;
#pragma unroll
        for (int o = 1; o < 64; o <<= 1) {
            unsigned n = __shfl_up(v, o, 64);
            if (lane >= o) v += n;
        }
        if (lane == 63) wsum[wave] = v;
        my_base = v - my_tot;
    }
    __syncthreads();
    if (tid < BINS) {
        unsigned add = 0;
#pragma unroll
        for (int w2 = 0; w2 < 4; ++w2) { if (w2 < wave) add += wsum[w2]; }
        offs[tid] = my_base + add + my_pref;
    }

    // --- rank all chunks in parallel (elements live in registers) ----------
    unsigned kr[CHUNKS], pr[CHUNKS], dr[CHUNKS], rr[CHUNKS];
#pragma unroll
    for (int c = 0; c < CHUNKS; ++c) {
        int idx = c * SCTH + tid;
        unsigned key, pay;
        if (PASS == 0) {
            key = desc_key(scores[segbase + gbase + idx]);
            pay = (unsigned)(gbase + idx);
        } else {
            key = keyIn[segbase + gbase + idx];
            pay = payIn[segbase + gbase + idx];
        }
        unsigned d = (key >> (PASS * 8)) & 255u;
        unsigned long long peers = ~0ull;
#pragma unroll
        for (int b = 0; b < 8; ++b) {
            unsigned long long vote = __ballot((d >> b) & 1u);
            peers &= ((d >> b) & 1u) ? vote : ~vote;
        }
        unsigned rank = (unsigned)__popcll(peers & lmask);
        if (rank == 0) whist[c * 8 + wave][d] = (unsigned)__popcll(peers);
        kr[c] = key; pr[c] = pay; dr[c] = d; rr[c] = rank;
    }
    __syncthreads();

    // --- column prefix over (chunk,wave) + local digit bases ----------------
    unsigned my_ltot = 0, my_lpart = 0;
    if (tid < BINS) {
        unsigned run = 0;
#pragma unroll
        for (int i = 0; i < CHUNKS * 8; ++i) {
            unsigned v = whist[i][tid];
            whist[i][tid] = run;
            run += v;
        }
        my_ltot = run;
        unsigned v = run;
#pragma unroll
        for (int o = 1; o < 64; o <<= 1) {
            unsigned n = __shfl_up(v, o, 64);
            if (lane >= o) v += n;
        }
        if (lane == 63) wsum[wave] = v;
        my_lpart = v - my_ltot;
    }
    __syncthreads();
    if (tid < BINS) {
        unsigned add = 0;
#pragma unroll
        for (int w2 = 0; w2 < 4; ++w2) { if (w2 < wave) add += wsum[w2]; }
        lexcl[tid] = my_lpart + add;
    }
    __syncthreads();

    // --- place into LDS at local sorted position ----------------------------
#pragma unroll
    for (int c = 0; c < CHUNKS; ++c) {
        unsigned j = lexcl[dr[c]] + whist[c * 8 + wave][dr[c]] + rr[c];
        skey[j] = kr[c];
        spay[j] = pr[c];
    }
    __syncthreads();

    // --- coalesced write-out ------------------------------------------------
#pragma unroll
    for (int c = 0; c < CHUNKS; ++c) {
        unsigned j = (unsigned)(c * SCTH + tid);
        unsigned key = skey[j];
        unsigned pay = spay[j];
        unsigned d = (key >> (PASS * 8)) & 255u;
        unsigned g = offs[d] + (j - lexcl[d]);
        if (PASS < 3) keyOut[segbase + g] = key;   // last pass: keys dead
        payOut[segbase + g] = pay;
    }
}

// ---------------------------------------------------------------------------
// Stage 3: gather boxes in sorted order. XCD-pinned by segment so each
// segment's 4.2MB boxes slice stays resident in one XCD's 4MB L2.
__global__ __launch_bounds__(256) void gather_kernel(
    const float* __restrict__ boxes8, const unsigned* __restrict__ pay,
    float* __restrict__ out)
{
    int id = blockIdx.x;
    int seg = id & 7;
    int bi  = id >> 3;                         // 0..1023
    int t   = threadIdx.x;
    int rowInSeg = bi * 128 + (t >> 1);
    int half = t & 1;
    size_t row = (size_t)seg * N_PER + rowInSeg;
    unsigned i = pay[row];
    const float4* src = (const float4*)(boxes8 + ((size_t)seg * N_PER + i) * 8);
    float4 v = src[half];
    ((float4*)(out + row * 8))[half] = v;
}

// ---------------------------------------------------------------------------
extern "C" void kernel_launch(void* const* d_in, const int* in_sizes, int n_in,
                              void* d_out, int out_size, void* d_ws, size_t ws_size,
                              hipStream_t stream)
{
    const float* scores = (const float*)d_in[0];
    const float* reg    = (const float*)d_in[1];
    const float* xyz    = (const float*)d_in[2];
    const float* anchor = (const float*)d_in[3];
    float* out = (float*)d_out;

    // workspace carve-up: 50,593,792 bytes (same footprint as before)
    char* ws = (char*)d_ws;
    float*    boxes8 = (float*)ws;
    size_t    off    = (size_t)TOTAL * 8 * sizeof(float);          // 33.55 MB
    unsigned* keyA = (unsigned*)(ws + off); off += (size_t)TOTAL * 4;
    unsigned* payA = (unsigned*)(ws + off); off += (size_t)TOTAL * 4;
    unsigned* keyB = (unsigned*)(ws + off); off += (size_t)TOTAL * 4;
    unsigned* payB = (unsigned*)(ws + off); off += (size_t)TOTAL * 4;
    unsigned short* hist = (unsigned short*)(ws + off);
    off += (size_t)NBATCH * NBLKSEG * BINS * sizeof(unsigned short);
    (void)ws_size; (void)in_sizes; (void)n_in; (void)out_size;

    decode_kernel<<<TOTAL / 256, 256, 0, stream>>>(scores, reg, xyz, anchor, boxes8);

    const int NG = NBATCH * NBLKSEG;   // 512 blocks, seg = id&7 (XCD pin)

    // pass 0: scores -> keyB/payB (keys derived on the fly, payload computed)
    hist_kernel<0><<<NG, 256, 0, stream>>>(scores, nullptr, hist);
    scatter_kernel<0><<<NG, SCTH, 0, stream>>>(scores, nullptr, nullptr,
                                               keyB, payB, hist);
    // pass 1: B -> A
    hist_kernel<1><<<NG, 256, 0, stream>>>(nullptr, keyB, hist);
    scatter_kernel<1><<<NG, SCTH, 0, stream>>>(nullptr, keyB, payB,
                                               keyA, payA, hist);
    // pass 2: A -> B
    hist_kernel<2><<<NG, 256, 0, stream>>>(nullptr, keyA, hist);
    scatter_kernel<2><<<NG, SCTH, 0, stream>>>(nullptr, keyA, payA,
                                               keyB, payB, hist);
    // pass 3: B -> A (payload only; keys dead after this pass)
    hist_kernel<3><<<NG, 256, 0, stream>>>(nullptr, keyB, hist);
    scatter_kernel<3><<<NG, SCTH, 0, stream>>>(nullptr, keyB, payB,
                                               nullptr, payA, hist);

    gather_kernel<<<NBATCH * (N_PER / 128), 256, 0, stream>>>(boxes8, payA, out);
}